// Round 1
// baseline (475.246 us; speedup 1.0000x reference)
//
#include <hip/hip_runtime.h>

// Problem: B=4, S=4096, L=256 decoder block.
// Key algebraic reductions (exact, not approximations):
//  - q[b,s,:] = cp_s * (tp_s*wq0 + ti_s*wq1 + wqb) -> rank-3 in L.
//    scores[b,s,t] = scale * x_s^T M x_t,  x_t = cp_t*(tp_t, ti_t, 1),
//    M[i][j] = dot(q_vec_i, k_vec_j) over L=256 (9 precomputed dots).
//  - v[b,t,:] = ti_t*wv0 + wvb  (rank-1), and sum_t attn = 1, so
//    tar_attn[b,s,:] = A_s*wv0 + wvb with A_s = (sum w_t*ti_t)/(sum w_t).
//  - h[b,s,j] = A_s*c1[j] + cp_s*c2[j] + c3[j], c1 = wv0@a2_w,
//    c2 = a3_w[0], c3 = wvb@a2_w + a2_b + a3_b.
//  - mask * -1e9 underflows to exactly 0 weight after softmax in fp32,
//    so we apply causality structurally (t <= s) and skip max-subtraction
//    (|score| ~ O(1); softmax is shift-invariant).

#define SEQ 4096
#define NB 4

// ws float layout:
//   [0..8]     M (row-major)
//   [16..143]  c1
//   [160..287] c2
//   [288..415] c3
//   [512..]    A (NB*SEQ floats)

__global__ __launch_bounds__(256) void pre_kernel(
    const float* __restrict__ wq_w, const float* __restrict__ wq_b,
    const float* __restrict__ wk_w, const float* __restrict__ wk_b,
    const float* __restrict__ wv_w, const float* __restrict__ wv_b,
    const float* __restrict__ a2_w, const float* __restrict__ a2_b,
    const float* __restrict__ a3_w, const float* __restrict__ a3_b,
    float* __restrict__ ws)
{
    int tid = threadIdx.x;
    if (tid < 128) {
        float c1 = 0.f, c3 = 0.f;
        for (int l = 0; l < 256; ++l) {
            float a2 = a2_w[l * 128 + tid];
            c1 += wv_w[l] * a2;
            c3 += wv_b[l] * a2;
        }
        ws[16 + tid]  = c1;
        ws[160 + tid] = a3_w[tid];
        ws[288 + tid] = c3 + a2_b[tid] + a3_b[tid];
    } else if (tid < 128 + 9) {
        int idx = tid - 128;
        int i = idx / 3, j = idx % 3;
        const float* qv = (i == 0) ? wq_w : (i == 1) ? (wq_w + 256) : wq_b;
        const float* kv = (j == 0) ? wk_w : (j == 1) ? (wk_w + 256) : wk_b;
        float m = 0.f;
        for (int l = 0; l < 256; ++l) m += qv[l] * kv[l];
        ws[i * 3 + j] = m;
    }
}

// One wave handles rows s=r and s=SEQ-1-r of the same batch: total work per
// wave is uniform (4097 elements) -> perfect load balance. 8192 waves total.
__global__ __launch_bounds__(256) void attn_kernel(
    const float* __restrict__ tp,   // tar_position  B*S
    const float* __restrict__ cp,   // current_pos   B*S
    const float* __restrict__ ti,   // tar_inp       B*S
    const float* __restrict__ ws,   // M at [0..8]
    float* __restrict__ A)          // B*S
{
    const int wave = (blockIdx.x * blockDim.x + threadIdx.x) >> 6; // 0..8191
    const int lane = threadIdx.x & 63;
    const int b = wave >> 11;       // 2048 waves per batch
    const int r = wave & 2047;

    const float M00 = ws[0], M01 = ws[1], M02 = ws[2];
    const float M10 = ws[3], M11 = ws[4], M12 = ws[5];
    const float M20 = ws[6], M21 = ws[7], M22 = ws[8];
    const float scale = 0.0625f;    // 1/sqrt(256)

    const float* __restrict__ tpb = tp + b * SEQ;
    const float* __restrict__ cpb = cp + b * SEQ;
    const float* __restrict__ tib = ti + b * SEQ;

    #pragma unroll
    for (int pick = 0; pick < 2; ++pick) {
        const int s = pick ? (SEQ - 1 - r) : r;
        const float cps = cpb[s], tps = tpb[s], tis = tib[s];
        const float x0 = cps * tps, x1 = cps * tis, x2 = cps;
        // d = scale * M^T x_s ; score[t] = cp_t * (d0*tp_t + d1*ti_t + d2)
        const float d0 = scale * (M00 * x0 + M10 * x1 + M20 * x2);
        const float d1 = scale * (M01 * x0 + M11 * x1 + M21 * x2);
        const float d2 = scale * (M02 * x0 + M12 * x1 + M22 * x2);

        float lsum = 0.f, asum = 0.f;
        for (int t = lane; t <= s; t += 64) {
            const float cpt = cpb[t];
            const float tpt = tpb[t];
            const float tit = tib[t];
            const float sc = cpt * (d0 * tpt + d1 * tit + d2);
            const float w = __expf(sc);
            lsum += w;
            asum += w * tit;
        }
        #pragma unroll
        for (int off = 32; off; off >>= 1) {
            lsum += __shfl_down(lsum, off, 64);
            asum += __shfl_down(asum, off, 64);
        }
        if (lane == 0) A[b * SEQ + s] = asum / lsum;
    }
}

// One thread per position: h(128) -> leaky -> @a4(128x32) -> leaky -> @a5(32x2)
__global__ __launch_bounds__(64) void mlp_kernel(
    const float* __restrict__ A,    // B*S
    const float* __restrict__ cp,   // B*S
    const float* __restrict__ ws,   // c1/c2/c3
    const float* __restrict__ a4_w, // 128*32
    const float* __restrict__ a4_b, // 32
    const float* __restrict__ a5_w, // 32*2
    const float* __restrict__ a5_b, // 2
    float* __restrict__ out)        // B*S*2
{
    __shared__ float sc1[128], sc2[128], sc3[128];
    __shared__ float sa4[128 * 32];
    const int tid = threadIdx.x;
    for (int i = tid; i < 128; i += 64) {
        sc1[i] = ws[16 + i];
        sc2[i] = ws[160 + i];
        sc3[i] = ws[288 + i];
    }
    for (int i = tid; i < 128 * 32; i += 64) sa4[i] = a4_w[i];
    __syncthreads();

    const int p = blockIdx.x * 64 + tid;   // 0..16383
    const float Av = A[p], cpv = cp[p];

    float acc[32];
    #pragma unroll
    for (int j2 = 0; j2 < 32; ++j2) acc[j2] = a4_b[j2];

    for (int j = 0; j < 128; ++j) {
        float h = Av * sc1[j] + cpv * sc2[j] + sc3[j];
        h = (h >= 0.f) ? h : 0.2f * h;
        #pragma unroll
        for (int j2 = 0; j2 < 32; ++j2) acc[j2] += h * sa4[j * 32 + j2];
    }

    float o0 = a5_b[0], o1 = a5_b[1];
    #pragma unroll
    for (int j2 = 0; j2 < 32; ++j2) {
        const float h2 = (acc[j2] >= 0.f) ? acc[j2] : 0.2f * acc[j2];
        o0 += h2 * a5_w[j2 * 2 + 0];
        o1 += h2 * a5_w[j2 * 2 + 1];
    }
    out[p * 2 + 0] = o0;
    out[p * 2 + 1] = o1;
}

extern "C" void kernel_launch(void* const* d_in, const int* in_sizes, int n_in,
                              void* d_out, int out_size, void* d_ws, size_t ws_size,
                              hipStream_t stream) {
    const float* tp   = (const float*)d_in[0];
    const float* cp   = (const float*)d_in[1];
    const float* ti   = (const float*)d_in[2];
    // d_in[3] = training (unused), d_in[4] = pos_mask (unused),
    // d_in[5] = tar_mask (causal triu -> applied structurally)
    const float* wq_w = (const float*)d_in[6];
    const float* wq_b = (const float*)d_in[7];
    const float* wk_w = (const float*)d_in[8];
    const float* wk_b = (const float*)d_in[9];
    const float* wv_w = (const float*)d_in[10];
    const float* wv_b = (const float*)d_in[11];
    const float* a2_w = (const float*)d_in[12];
    const float* a2_b = (const float*)d_in[13];
    const float* a3_w = (const float*)d_in[14];
    const float* a3_b = (const float*)d_in[15];
    const float* a4_w = (const float*)d_in[16];
    const float* a4_b = (const float*)d_in[17];
    const float* a5_w = (const float*)d_in[18];
    const float* a5_b = (const float*)d_in[19];

    float* ws  = (float*)d_ws;
    float* A   = ws + 512;
    float* out = (float*)d_out;

    hipLaunchKernelGGL(pre_kernel, dim3(1), dim3(256), 0, stream,
                       wq_w, wq_b, wk_w, wk_b, wv_w, wv_b,
                       a2_w, a2_b, a3_w, a3_b, ws);
    // 8192 waves (2 rows each) = 2048 blocks x 256 threads
    hipLaunchKernelGGL(attn_kernel, dim3(2048), dim3(256), 0, stream,
                       tp, cp, ti, ws, A);
    // 16384 positions, 1 thread each
    hipLaunchKernelGGL(mlp_kernel, dim3(256), dim3(64), 0, stream,
                       A, cp, ws, a4_w, a4_b, a5_w, a5_b, out);
}